// Round 3
// baseline (483.388 us; speedup 1.0000x reference)
//
#include <hip/hip_runtime.h>

// EvoBinarizedLayer: out[p,b,o] = x@W0 + (1-x)@W1 = x@(W0-W1) + colsum_i(W1)
// x:[32,512,1024] {0,1} fp32; w:[2,32,1024,1024] {0,1} fp32; out fp32. Exact in bf16.
//
// R3: two-pass. R2 (single-pass, 170us) was latency-convoy bound: fp32 staging
// forced register-coupled vmcnt(0) + VALU convert + conflicted LDS transpose
// between two barriers every 32-k step; HBM sat at 37%, no pipe >13% busy.
// Pass1: barrier-free streaming transform (w -> diff-bf16, TRANSPOSED [p][o][k];
//        x -> bf16; colsum) -- the access pattern class that hits ~6.5 TB/s.
// Pass2: m97-structure bf16 GEMM, global_load_lds dwordx4 both operands
//        (no staging VALU, no per-wave load-data dependency), BK=64,
//        XOR-chunk swizzle for conflict-free b128 frag reads.

namespace {

constexpr int PP = 32;
constexpr int BB = 512;
constexpr int II = 1024;
constexpr int OO = 1024;

typedef __attribute__((ext_vector_type(8))) short bf16x8;
typedef __attribute__((ext_vector_type(4))) float f32x4;

// fp32 -> bf16 truncation: exact for {0,+-1}. Pack two (lo,hi) into u32.
__device__ __forceinline__ unsigned pk2(float lo, float hi) {
    return (__float_as_uint(lo) >> 16) | (__float_as_uint(hi) & 0xFFFF0000u);
}

// ---------------------------------------------------------------- pass 1 ----
// blocks 0..255:   w-transform. block = (p = b>>3, o-tile = b&7 of 128 o), all k.
//   thread: 4 o-cols (o0+4*og), 8 k-rows per iter (k = 64*it + 8*kg + j).
//   Register transpose: per o-col pack 8 k-contiguous bf16 -> one dwordx4 store.
//   colsum(W1) accumulated in registers across all k, reduced via LDS at end.
// blocks 256..511: x fp32 -> bf16 streaming convert.
__global__ __launch_bounds__(256, 2) void ebl_prep(const float* __restrict__ x,
                                                   const float* __restrict__ w,
                                                   unsigned short* __restrict__ dWT,
                                                   unsigned short* __restrict__ xbf,
                                                   float* __restrict__ colsum) {
    const int t = (int)threadIdx.x;
    const int bid = (int)blockIdx.x;

    if (bid < 256) {
        const int p  = bid >> 3;
        const int o0 = (bid & 7) * 128;
        const int og = t & 31;       // o-group: 4 cols at o0 + 4*og
        const int kg = t >> 5;       // 0..7: k-phase
        const int o  = o0 + 4 * og;
        const float* w0p = w + (size_t)p * (II * OO) + o;
        const float* w1p = w + (size_t)(PP + p) * (II * OO) + o;

        float cs0 = 0.f, cs1 = 0.f, cs2 = 0.f, cs3 = 0.f;

        for (int it = 0; it < 16; ++it) {
            const int kb = 64 * it + 8 * kg;
            const float* r0 = w0p + (size_t)kb * OO;
            const float* r1 = w1p + (size_t)kb * OO;
            f32x4 q0[8], q1[8];
#pragma unroll
            for (int j = 0; j < 8; ++j) q0[j] = *(const f32x4*)(r0 + (size_t)j * OO);
#pragma unroll
            for (int j = 0; j < 8; ++j) q1[j] = *(const f32x4*)(r1 + (size_t)j * OO);

#pragma unroll
            for (int c = 0; c < 4; ++c) {
                uint4 st;
                st.x = pk2(q0[0][c] - q1[0][c], q0[1][c] - q1[1][c]);
                st.y = pk2(q0[2][c] - q1[2][c], q0[3][c] - q1[3][c]);
                st.z = pk2(q0[4][c] - q1[4][c], q0[5][c] - q1[5][c]);
                st.w = pk2(q0[6][c] - q1[6][c], q0[7][c] - q1[7][c]);
                // dW^T[p][o+c][kb..kb+8) : 16B k-contiguous store
                *(uint4*)(&dWT[((size_t)p * OO + o + c) * II + kb]) = st;
            }
#pragma unroll
            for (int j = 0; j < 8; ++j) {
                cs0 += q1[j].x; cs1 += q1[j].y; cs2 += q1[j].z; cs3 += q1[j].w;
            }
        }

        __shared__ float Scr[8 * 128];
        *(f32x4*)(&Scr[kg * 128 + 4 * og]) = (f32x4){cs0, cs1, cs2, cs3};
        __syncthreads();
        if (t < 128) {
            float s = 0.f;
#pragma unroll
            for (int g = 0; g < 8; ++g) s += Scr[g * 128 + t];
            colsum[p * OO + o0 + t] = s;
        }
    } else {
        // x convert: 256 blocks x 65536 f32 each.
        const size_t base = (size_t)(bid - 256) * 65536;
        for (int it = 0; it < 16; ++it) {
#pragma unroll
            for (int j = 0; j < 4; ++j) {
                const size_t idx = base + (size_t)it * 4096 + j * 1024 + 4 * t;
                f32x4 v = *(const f32x4*)(x + idx);
                *(uint2*)(&xbf[idx]) = make_uint2(pk2(v.x, v.y), pk2(v.z, v.w));
            }
        }
    }
}

// ---------------------------------------------------------------- pass 2 ----
// 128x128 tile, BK=64, 256 threads, wave tile 64x64 (2x2 waves).
// LDS: As/Bs [128 rows][64 k] bf16 (128B rows = 8 chunks of 16B), chunk-XOR
// swizzled: stored chunk j holds global k-chunk j ^ (row&7). DMA writes are
// contiguous (conflict-free); b128 frag reads cover all 32 banks uniformly.
__device__ __forceinline__ void load_lds16(const unsigned short* g, unsigned short* l) {
    __builtin_amdgcn_global_load_lds(
        (const __attribute__((address_space(1))) unsigned int*)g,
        (__attribute__((address_space(3))) unsigned int*)l, 16, 0, 0);
}

__global__ __launch_bounds__(256, 3) void ebl_gemm(const unsigned short* __restrict__ xbf,
                                                   const unsigned short* __restrict__ dWT,
                                                   const float* __restrict__ colsum,
                                                   float* __restrict__ out) {
    __shared__ __align__(16) unsigned short As[128 * 64];  // 16 KB
    __shared__ __align__(16) unsigned short Bs[128 * 64];  // 16 KB

    const int t  = (int)threadIdx.x;
    const int l  = t & 63;
    const int wv = t >> 6;     // 0..3
    const int wm = wv & 1;
    const int wn = wv >> 1;
    const int lq = l >> 4;
    const int ln = l & 15;

    const int p  = (int)blockIdx.z;
    const int b0 = (int)blockIdx.y * 128;
    const int o0 = (int)blockIdx.x * 128;

    const unsigned short* Ag = xbf + ((size_t)p * BB + b0) * II;
    const unsigned short* Bg = dWT + ((size_t)p * OO + o0) * II;

    // DMA lane mapping: instr q stages 8 rows (r0=8*(4wv+q)); lane i -> LDS
    // base + 16B*i = row r0+(i>>3), stored chunk i&7. Global chunk = (i&7)^(row&7).
    const int ri = l >> 3, sj = l & 7;
    int gof[4], lbase[4];
#pragma unroll
    for (int q = 0; q < 4; ++q) {
        const int r0  = 8 * (4 * wv + q);
        const int row = r0 + ri;
        gof[q]   = row * II + 8 * (sj ^ (row & 7));
        lbase[q] = r0 * 64;
    }

    // Frag read offsets (elements): row*64 + 8*((4s+lq)^(row&7)), row&7 == ln&7.
    int aoff[2][4], boff[2][4];
#pragma unroll
    for (int s = 0; s < 2; ++s)
#pragma unroll
        for (int mt = 0; mt < 4; ++mt) {
            const int j = 8 * ((4 * s + lq) ^ (ln & 7));
            aoff[s][mt] = (wm * 64 + mt * 16 + ln) * 64 + j;
            boff[s][mt] = (wn * 64 + mt * 16 + ln) * 64 + j;
        }

    f32x4 acc[4][4];
#pragma unroll
    for (int mt = 0; mt < 4; ++mt)
#pragma unroll
        for (int nt = 0; nt < 4; ++nt)
            acc[mt][nt] = (f32x4){0.f, 0.f, 0.f, 0.f};

    for (int kk = 0; kk < II; kk += 64) {
#pragma unroll
        for (int q = 0; q < 4; ++q) {
            load_lds16(Ag + gof[q] + kk, As + lbase[q]);
            load_lds16(Bg + gof[q] + kk, Bs + lbase[q]);
        }
        __syncthreads();  // drains vmcnt(0): DMA complete

#pragma unroll
        for (int s = 0; s < 2; ++s) {
            bf16x8 af[4], bfv[4];
#pragma unroll
            for (int mt = 0; mt < 4; ++mt) af[mt] = *(const bf16x8*)(As + aoff[s][mt]);
#pragma unroll
            for (int nt = 0; nt < 4; ++nt) bfv[nt] = *(const bf16x8*)(Bs + boff[s][nt]);
#pragma unroll
            for (int mt = 0; mt < 4; ++mt)
#pragma unroll
                for (int nt = 0; nt < 4; ++nt)
                    acc[mt][nt] = __builtin_amdgcn_mfma_f32_16x16x32_bf16(
                        af[mt], bfv[nt], acc[mt][nt], 0, 0, 0);
        }
        __syncthreads();  // all frag reads done before next DMA overwrites
    }

    // Epilogue: C/D layout col=lane&15, row=quad*4+reg (m89/m91-verified).
    float cs[4];
#pragma unroll
    for (int nt = 0; nt < 4; ++nt)
        cs[nt] = colsum[p * OO + o0 + wn * 64 + nt * 16 + ln];

    float* op = out + ((size_t)p * BB + b0) * OO + o0;
#pragma unroll
    for (int nt = 0; nt < 4; ++nt) {
        const int ocol = wn * 64 + nt * 16 + ln;
#pragma unroll
        for (int mt = 0; mt < 4; ++mt) {
            const int row = wm * 64 + mt * 16 + lq * 4;
#pragma unroll
            for (int r = 0; r < 4; ++r)
                op[(size_t)(row + r) * OO + ocol] = acc[mt][nt][r] + cs[nt];
        }
    }
}

}  // namespace

extern "C" void kernel_launch(void* const* d_in, const int* in_sizes, int n_in,
                              void* d_out, int out_size, void* d_ws, size_t ws_size,
                              hipStream_t stream) {
    const float* x = (const float*)d_in[0];
    const float* w = (const float*)d_in[1];
    float* out = (float*)d_out;

    // Workspace layout (needs ~100.1 MB; ws is ~1 GB per harness poison fill):
    unsigned short* dWT = (unsigned short*)d_ws;                          // 64 MiB
    unsigned short* xbf = (unsigned short*)((char*)d_ws + (64u << 20));   // 32 MiB
    float* colsum = (float*)((char*)d_ws + (96u << 20));                  // 128 KiB

    ebl_prep<<<dim3(512, 1, 1), dim3(256, 1, 1), 0, stream>>>(x, w, dWT, xbf, colsum);
    ebl_gemm<<<dim3(OO / 128, BB / 128, PP), dim3(256, 1, 1), 0, stream>>>(
        xbf, dWT, colsum, out);
}